// Round 16
// baseline (821.050 us; speedup 1.0000x reference)
//
#include <hip/hip_runtime.h>

#define NN 64
#define NI 6
#define TT 1024
#define BB 1024
#define TB (TT * BB)
#define NSCALE 0.13416407864998738f        // sqrt(2/alpha) * sigma
#define ARNSCALE 0.013416407864998739f     // alpha * NSCALE
#define RREC 72                            // rnu record: 64 rn' (-> x) + 6 uterm + 2 pad(0)
#define BSTRIDE (TT * RREC)                // 73728 floats per batch

__device__ __forceinline__ float rdlane(float v, int l) {
    return __int_as_float(__builtin_amdgcn_readlane(__float_as_int(v), l));
}

// ---------------- Pass 1: build rnu[b][t][72] in d_ws ----------------
// record[0..63]  = ARNSCALE * rn[n][t][b]   (transposed, n contiguous)
// record[64..69] = u[i][t][b] + NSCALE*inn[i][t][b];  [70..71] = 0
__global__ __launch_bounds__(256) void build_rnu(
    const float* __restrict__ u,
    const float* __restrict__ rn,
    const float* __restrict__ inn,
    float* __restrict__ rnu)
{
    const int blk = blockIdx.x;
    const int t   = blk >> 4;
    const int b0  = (blk & 15) * 64;
    const int tid = threadIdx.x;

    __shared__ float lds[64][65];

    {   // read rn 64n x 64b tile (coalesced along b), store transposed + prescale
        const int c  = tid & 63;
        const int r0 = tid >> 6;
#pragma unroll
        for (int it = 0; it < 16; ++it) {
            const int n = 4 * it + r0;
            lds[c][n] = ARNSCALE * rn[n * TB + t * BB + b0 + c];
        }
    }
    __syncthreads();
    {   // write 64 b-rows, 64 n contiguous each (coalesced)
        const int cn = tid & 63;
        const int r0 = tid >> 6;
#pragma unroll
        for (int it = 0; it < 16; ++it) {
            const int r = 4 * it + r0;
            rnu[(b0 + r) * BSTRIDE + t * RREC + cn] = lds[r][cn];
        }
    }
    {   // uterm (+ zero pad) — 8 floats per b
        const int i  = tid & 7;
        const int br = tid >> 3;
#pragma unroll
        for (int it = 0; it < 2; ++it) {
            const int b = br + 32 * it;
            float v = 0.0f;
            if (i < NI) {
                const int g = i * TB + t * BB + b0 + b;
                v = fmaf(NSCALE, inn[g], u[g]);
            }
            rnu[(b0 + b) * BSTRIDE + t * RREC + 64 + i] = v;
        }
    }
}

// ---------------- Pass 2: recurrence, bf16-packed LDS broadcast ----------------
// 1024 blocks x 64 thr (4 waves/CU). lane = neuron, block = batch.
// Round-13/15 diagnosis: wall = shared per-CU LDS return pipe (4 waves x 18
// ds_read_b128 x ~12cyc = 864 cyc/step). Fix: broadcast row packed as bf16 ->
// 8 b128 for x + 2 b128 for f32 uterm = 10 b128/wave/step (480 cyc/CU).
// Carried x stays f32; only the broadcast copy is RNE-rounded to bf16.
__global__ __launch_bounds__(64, 1) void latent_rnn_b16(
    const float* __restrict__ rn_in,  // (B, T, 72) — reads
    float* __restrict__ x_out,        // (B, T, 72) — x writeback (same buffer)
    const float* __restrict__ Winp,   // (64, 6)
    const float* __restrict__ Wrec)   // (64, 64)
{
    const int hw = blockIdx.x;
    const int b  = (hw & 7) * 128 + (hw >> 3);   // XCD swizzle: 128 batches/XCD
    const int n  = threadIdx.x;

    // row: x as bf16[64] (128B) | pad (16B) | uterm f32[8] (32B)
    struct __align__(16) Row { unsigned short x[64]; unsigned short pad[8]; float ut[8]; };
    __shared__ Row xs[2];

    // ---- per-lane weights (live in AGPRs, read directly by fma — free) ----
    float w[NN];
#pragma unroll
    for (int k = 0; k < NN; k += 4) {
        const float4 w4 = *reinterpret_cast<const float4*>(Wrec + n * NN + k);
        w[k] = w4.x; w[k + 1] = w4.y; w[k + 2] = w4.z; w[k + 3] = w4.w;
    }
    float wu[8];
#pragma unroll
    for (int i = 0; i < NI; ++i) wu[i] = Winp[n * NI + i];
    wu[6] = 0.0f; wu[7] = 0.0f;

    const float* rptr = rn_in + b * BSTRIDE + n;             // rn' lane view
    const float* uptr = rn_in + b * BSTRIDE + 64 + (n & 7);  // uterm lane view
    float*       xdst = x_out + b * BSTRIDE + n;             // x writeback view

    // ---- init parity 0: x[0] = 0 (bf16 0), uterm(0) ----
    xs[0].x[n] = 0;
    if (n < 8) xs[0].ut[n] = uptr[0];

    // prefetch rings (depth 4): rnb = rn'(t), utb = uterm(t+1)
    float rnb[4], utb[4];
#pragma unroll
    for (int d = 0; d < 4; ++d) {
        rnb[d] = rptr[d * RREC];
        utb[d] = uptr[(d + 1) * RREC];
    }

    float xreg = 0.0f;

#define STEP(tcur, slot, P)                                                   \
    do {                                                                      \
        const float rcur = rnb[slot];                                         \
        const float ucur = utb[slot];   /* uterm(t+1) */                      \
        { const int tp = ((tcur) + 4 < TT - 2) ? (tcur) + 4 : TT - 2;         \
          rnb[slot] = rptr[tp * RREC]; }                                      \
        { const int tq = ((tcur) + 5 < TT - 2) ? (tcur) + 5 : TT - 2;         \
          utb[slot] = uptr[tq * RREC]; }                                      \
        /* broadcast-read x row (8 b128 of packed bf16) + uterm (2 b128) */   \
        const float4* xrow = reinterpret_cast<const float4*>(&xs[P].x[0]);    \
        float a0 = 0.f, a1 = 0.f, a2 = 0.f, a3 = 0.f;                         \
        _Pragma("unroll")                                                     \
        for (int q = 0; q < 8; ++q) {                                         \
            const float4 v = xrow[q];                                         \
            const unsigned u0 = __float_as_uint(v.x);                         \
            const unsigned u1 = __float_as_uint(v.y);                         \
            const unsigned u2 = __float_as_uint(v.z);                         \
            const unsigned u3 = __float_as_uint(v.w);                         \
            a0 = fmaf(__uint_as_float(u0 << 16),          w[8*q + 0], a0);    \
            a1 = fmaf(__uint_as_float(u0 & 0xffff0000u),  w[8*q + 1], a1);    \
            a2 = fmaf(__uint_as_float(u1 << 16),          w[8*q + 2], a2);    \
            a3 = fmaf(__uint_as_float(u1 & 0xffff0000u),  w[8*q + 3], a3);    \
            a0 = fmaf(__uint_as_float(u2 << 16),          w[8*q + 4], a0);    \
            a1 = fmaf(__uint_as_float(u2 & 0xffff0000u),  w[8*q + 5], a1);    \
            a2 = fmaf(__uint_as_float(u3 << 16),          w[8*q + 6], a2);    \
            a3 = fmaf(__uint_as_float(u3 & 0xffff0000u),  w[8*q + 7], a3);    \
        }                                                                     \
        const float4 iv0 = *reinterpret_cast<const float4*>(&xs[P].ut[0]);    \
        const float4 iv1 = *reinterpret_cast<const float4*>(&xs[P].ut[4]);    \
        a0 = fmaf(iv0.x, wu[0], a0); a1 = fmaf(iv0.y, wu[1], a1);             \
        a2 = fmaf(iv0.z, wu[2], a2); a3 = fmaf(iv0.w, wu[3], a3);             \
        a0 = fmaf(iv1.x, wu[4], a0); a1 = fmaf(iv1.y, wu[5], a1);             \
        const float pre = (a0 + a1) + (a2 + a3);                              \
        const float xn  = fmaf(0.9f, xreg,                                    \
                               fmaf(0.1f, fmaxf(pre, 0.f), rcur));            \
        xreg = xn;                                                            \
        /* RNE bf16 of xn -> broadcast copy for next step */                  \
        unsigned pk;                                                          \
        asm("v_cvt_pk_bf16_f32 %0, %1, %2" : "=v"(pk) : "v"(xn), "v"(xn));    \
        xs[(P) ^ 1].x[n] = (unsigned short)pk;                                \
        if (n < 8) xs[(P) ^ 1].ut[n] = ucur;   /* uterm[t+1] */               \
        xdst[(tcur) * RREC] = xn;              /* record[t] <- x[t+1] (f32) */\
    } while (0)

#pragma unroll 1
    for (int t = 0; t < 1020; t += 4) {
        STEP(t + 0, 0, 0);
        STEP(t + 1, 1, 1);
        STEP(t + 2, 2, 0);
        STEP(t + 3, 3, 1);
    }
    STEP(1020, 0, 0);
    STEP(1021, 1, 1);
    STEP(1022, 2, 0);
#undef STEP
}

// ---------------- Pass 3: transpose + fused output projection ----------------
// states[n][t][b] = (t==0) ? 0 : rnu[b][t-1][n];  outputs = states @ Wout^T.
__global__ __launch_bounds__(256) void trans_out(
    const float* __restrict__ rnu,
    const float* __restrict__ Wout,     // (2, 64)
    float* __restrict__ states,         // (64, T, B)
    float* __restrict__ outputs)        // (2, T, B)
{
    const int blk = blockIdx.x;
    const int t   = blk >> 4;
    const int b0  = (blk & 15) * 64;
    const int tid = threadIdx.x;

    __shared__ float xt[64][65];   // [b][n]
    __shared__ float wo[2][64];

    if (tid < 128) wo[tid >> 6][tid & 63] = Wout[tid];

    const int col = tid & 63;
    const int r0  = tid >> 6;
    if (t == 0) {
#pragma unroll
        for (int it = 0; it < 16; ++it) xt[4 * it + r0][col] = 0.0f;
    } else {
#pragma unroll
        for (int it = 0; it < 16; ++it) {
            const int r = 4 * it + r0;   // batch within tile
            xt[r][col] = rnu[(b0 + r) * BSTRIDE + (t - 1) * RREC + col];
        }
    }
    __syncthreads();

#pragma unroll
    for (int it = 0; it < 16; ++it) {
        const int n = 4 * it + r0;
        states[n * TB + t * BB + b0 + col] = xt[col][n];
    }

    if (tid < 128) {
        const int o  = tid >> 6;
        const int bb = tid & 63;
        float acc = 0.0f;
#pragma unroll
        for (int k = 0; k < NN; ++k) acc = fmaf(xt[bb][k], wo[o][k], acc);
        outputs[o * TB + t * BB + b0 + bb] = acc;
    }
}

// ---------------- Fallback (no-workspace path, proven correct) ----------------
#define BARRIER() do {                                                        \
    __builtin_amdgcn_sched_barrier(0);                                        \
    asm volatile("s_waitcnt lgkmcnt(0)\n\ts_barrier" ::: "memory");           \
    __builtin_amdgcn_sched_barrier(0);                                        \
} while (0)

__global__ __launch_bounds__(256, 1) void latent_rnn_fb(
    const float* __restrict__ u, const float* __restrict__ rn,
    const float* __restrict__ inn, const float* __restrict__ Winp,
    const float* __restrict__ Wrec, float* __restrict__ states)
{
    const int hw  = blockIdx.x;
    const int lb  = (hw & 7) * 32 + (hw >> 3);
    const int b0  = lb * 4;
    const int tid = threadIdx.x;
    const int l   = tid & 63;
    const int w   = tid >> 6;
    const int n   = tid >> 2;
    const int bs  = tid & 3;

    __shared__ float rnT[2][NN][5];
    __shared__ float xT[2][NN][5];
    __shared__ float iT[2][4][8];

    float wreg[NN];
#pragma unroll
    for (int k = 0; k < NN; k += 4) {
        const float4 w4 = *reinterpret_cast<const float4*>(Wrec + l * NN + k);
        wreg[k] = w4.x; wreg[k+1] = w4.y; wreg[k+2] = w4.z; wreg[k+3] = w4.w;
    }
    float wi[NI];
#pragma unroll
    for (int i = 0; i < NI; ++i) wi[i] = Winp[l * NI + i];

    const float* rsrc = rn + n * TB + b0 + bs;
    float*       sdst = states + n * TB + b0 + bs;
    const bool  ist  = (tid < NI * 4);
    const int   ii   = tid >> 2;
    const int   ib   = tid & 3;
    const float* usrc = u   + ii * TB + b0 + ib;
    const float* isrc = inn + ii * TB + b0 + ib;

    rnT[0][n][bs] = rsrc[0];
    if (ist) iT[0][ib][ii] = fmaf(NSCALE, isrc[0], usrc[0]);
    xT[0][l][w] = 0.0f;

    float rnPF[4], uPF[4], iPF[4];
#pragma unroll
    for (int d = 0; d < 4; ++d) {
        rnPF[d] = rsrc[(d + 1) * BB];
        if (ist) { uPF[d] = usrc[(d + 1) * BB]; iPF[d] = isrc[(d + 1) * BB]; }
    }
    __syncthreads();

    float xreg = 0.0f;

#define FSTEP(tcur, slot, CC)                                                 \
  {                                                                           \
    sdst[(tcur) * BB] = xT[CC][n][bs];                                        \
    const float rcur = rnT[CC][l][w];                                         \
    const float4 iv0 = *reinterpret_cast<const float4*>(&iT[CC][w][0]);       \
    const float2 iv1 = *reinterpret_cast<const float2*>(&iT[CC][w][4]);       \
    float a0 = 0.f, a1 = 0.f, a2 = 0.f, a3 = 0.f;                             \
    _Pragma("unroll")                                                         \
    for (int k = 0; k < NN; k += 4) {                                         \
        a0 = fmaf(rdlane(xreg, k + 0), wreg[k + 0], a0);                      \
        a1 = fmaf(rdlane(xreg, k + 1), wreg[k + 1], a1);                      \
        a2 = fmaf(rdlane(xreg, k + 2), wreg[k + 2], a2);                      \
        a3 = fmaf(rdlane(xreg, k + 3), wreg[k + 3], a3);                      \
    }                                                                         \
    a0 = fmaf(iv0.x, wi[0], a0); a1 = fmaf(iv0.y, wi[1], a1);                 \
    a2 = fmaf(iv0.z, wi[2], a2); a3 = fmaf(iv0.w, wi[3], a3);                 \
    a0 = fmaf(iv1.x, wi[4], a0); a1 = fmaf(iv1.y, wi[5], a1);                 \
    const float pre = (a0 + a1) + (a2 + a3);                                  \
    const float xn  = fmaf(0.9f, xreg,                                        \
                           fmaf(0.1f, fmaxf(pre, 0.f), ARNSCALE * rcur));     \
    xreg = xn;                                                                \
    xT[(CC) ^ 1][l][w] = xn;                                                  \
    rnT[(CC) ^ 1][n][bs] = rnPF[slot];                                        \
    if (ist) iT[(CC) ^ 1][ib][ii] = fmaf(NSCALE, iPF[slot], uPF[slot]);       \
    { int tp = (tcur) + 5; if (tp > TT - 2) tp = TT - 2;                      \
      rnPF[slot] = rsrc[tp * BB];                                             \
      if (ist) { uPF[slot] = usrc[tp * BB]; iPF[slot] = isrc[tp * BB]; } }    \
    BARRIER();                                                                \
  }

#pragma unroll 1
    for (int t = 0; t < 1020; t += 4) {
        FSTEP(t + 0, 0, 0);
        FSTEP(t + 1, 1, 1);
        FSTEP(t + 2, 2, 0);
        FSTEP(t + 3, 3, 1);
    }
    FSTEP(1020, 0, 0);
    FSTEP(1021, 1, 1);
    FSTEP(1022, 2, 0);
#undef FSTEP

    sdst[(TT - 1) * BB] = xT[1][n][bs];
}

__global__ __launch_bounds__(256) void out_proj(
    const float* __restrict__ states,
    const float* __restrict__ Wout,
    float* __restrict__ outputs)
{
    const int g4 = (blockIdx.x * 256 + threadIdx.x) * 4;
    float4 a0 = {0.f, 0.f, 0.f, 0.f};
    float4 a1 = {0.f, 0.f, 0.f, 0.f};
#pragma unroll
    for (int k = 0; k < NN; ++k) {
        const float4 s = *reinterpret_cast<const float4*>(states + k * TB + g4);
        const float w0 = Wout[k];
        const float w1 = Wout[NN + k];
        a0.x = fmaf(s.x, w0, a0.x); a0.y = fmaf(s.y, w0, a0.y);
        a0.z = fmaf(s.z, w0, a0.z); a0.w = fmaf(s.w, w0, a0.w);
        a1.x = fmaf(s.x, w1, a1.x); a1.y = fmaf(s.y, w1, a1.y);
        a1.z = fmaf(s.z, w1, a1.z); a1.w = fmaf(s.w, w1, a1.w);
    }
    *reinterpret_cast<float4*>(outputs + g4)      = a0;
    *reinterpret_cast<float4*>(outputs + TB + g4) = a1;
}

extern "C" void kernel_launch(void* const* d_in, const int* in_sizes, int n_in,
                              void* d_out, int out_size, void* d_ws, size_t ws_size,
                              hipStream_t stream) {
    const float* u    = (const float*)d_in[0];
    const float* rn   = (const float*)d_in[1];
    const float* inn  = (const float*)d_in[2];
    const float* Winp = (const float*)d_in[3];
    const float* Wrec = (const float*)d_in[4];
    const float* Wout = (const float*)d_in[5];

    float* states  = (float*)d_out;                          // 64*1024*1024
    float* outputs = (float*)d_out + (size_t)NN * TT * BB;   // 2*1024*1024

    const size_t need = (size_t)BB * TT * RREC * sizeof(float);  // ~302 MB
    if (ws_size >= need) {
        float* rnu = (float*)d_ws;
        build_rnu<<<TT * 16, 256, 0, stream>>>(u, rn, inn, rnu);
        latent_rnn_b16<<<1024, 64, 0, stream>>>(rnu, rnu, Winp, Wrec);
        trans_out<<<TT * 16, 256, 0, stream>>>(rnu, Wout, states, outputs);
    } else {
        latent_rnn_fb<<<256, 256, 0, stream>>>(u, rn, inn, Winp, Wrec, states);
        out_proj<<<1024, 256, 0, stream>>>(states, Wout, outputs);
    }
}

// Round 17
// 625.837 us; speedup vs baseline: 1.3119x; 1.3119x over previous
//
#include <hip/hip_runtime.h>

#define NN 64
#define NI 6
#define TT 1024
#define BB 1024
#define TB (TT * BB)
#define NSCALE 0.13416407864998738f        // sqrt(2/alpha) * sigma
#define ARNSCALE 0.013416407864998739f     // alpha * NSCALE
#define RREC 72                            // rnu record: 64 rn' (-> x) + 6 uterm + 2 pad(0)
#define BSTRIDE (TT * RREC)                // 73728 floats per batch

__device__ __forceinline__ float rdlane(float v, int l) {
    return __int_as_float(__builtin_amdgcn_readlane(__float_as_int(v), l));
}

// ---------------- Pass 1: build rnu[b][t][72] in d_ws ----------------
// record[0..63]  = ARNSCALE * rn[n][t][b]   (transposed, n contiguous)
// record[64..69] = u[i][t][b] + NSCALE*inn[i][t][b];  [70..71] = 0
__global__ __launch_bounds__(256) void build_rnu(
    const float* __restrict__ u,
    const float* __restrict__ rn,
    const float* __restrict__ inn,
    float* __restrict__ rnu)
{
    const int blk = blockIdx.x;
    const int t   = blk >> 4;
    const int b0  = (blk & 15) * 64;
    const int tid = threadIdx.x;

    __shared__ float lds[64][65];

    {   // read rn 64n x 64b tile (coalesced along b), store transposed + prescale
        const int c  = tid & 63;
        const int r0 = tid >> 6;
#pragma unroll
        for (int it = 0; it < 16; ++it) {
            const int n = 4 * it + r0;
            lds[c][n] = ARNSCALE * rn[n * TB + t * BB + b0 + c];
        }
    }
    __syncthreads();
    {   // write 64 b-rows, 64 n contiguous each (coalesced)
        const int cn = tid & 63;
        const int r0 = tid >> 6;
#pragma unroll
        for (int it = 0; it < 16; ++it) {
            const int r = 4 * it + r0;
            rnu[(b0 + r) * BSTRIDE + t * RREC + cn] = lds[r][cn];
        }
    }
    {   // uterm (+ zero pad) — 8 floats per b
        const int i  = tid & 7;
        const int br = tid >> 3;
#pragma unroll
        for (int it = 0; it < 2; ++it) {
            const int b = br + 32 * it;
            float v = 0.0f;
            if (i < NI) {
                const int g = i * TB + t * BB + b0 + b;
                v = fmaf(NSCALE, inn[g], u[g]);
            }
            rnu[(b0 + b) * BSTRIDE + t * RREC + 64 + i] = v;
        }
    }
}

// ---------------- Pass 2: recurrence, split-dot LDS broadcast ----------------
// 1024 blocks x 64 thr (4 waves/CU). lane = neuron, block = batch.
// DS-pipe diet: lane n reads only HALF the x row (8 ds_read_b128, half h=n>>5)
// and computes two half-dots: P1 = row n over half h, P2 = row n^32 over half h.
// __shfl_xor(P2,32) delivers the missing half: pre[n] = P1 + shfl(P2).
// DS ops/step: 12 vs r13's 19, with IDENTICAL fma count (the r16 mistake was
// adding per-element unpack work). Carried x stays f32 everywhere.
__global__ __launch_bounds__(64, 1) void latent_rnn_split(
    const float* __restrict__ rn_in,  // (B, T, 72) — reads
    float* __restrict__ x_out,        // (B, T, 72) — x writeback (same buffer)
    const float* __restrict__ Winp,   // (64, 6)
    const float* __restrict__ Wrec)   // (64, 64)
{
    const int hw = blockIdx.x;
    const int b  = (hw & 7) * 128 + (hw >> 3);   // XCD swizzle: 128 batches/XCD
    const int n  = threadIdx.x;
    const int h  = n >> 5;                       // half of x this lane reads
    const int hb = 32 * h;                       // base column of that half
    const int np = n ^ 32;                       // partner neuron/lane

    __shared__ __align__(16) float xs[2][80];    // [parity][x(64) | uterm(8) | pad]

    // ---- permuted weight distribution ----
    // ws[j] = W[n ][hb+j]  (own row, own half)
    // wp[j] = W[np][hb+j]  (partner row, own half) -> partner's missing half
    float ws[32], wp[32];
#pragma unroll
    for (int j = 0; j < 32; j += 4) {
        const float4 a = *reinterpret_cast<const float4*>(Wrec + n  * NN + hb + j);
        const float4 c = *reinterpret_cast<const float4*>(Wrec + np * NN + hb + j);
        ws[j] = a.x; ws[j+1] = a.y; ws[j+2] = a.z; ws[j+3] = a.w;
        wp[j] = c.x; wp[j+1] = c.y; wp[j+2] = c.z; wp[j+3] = c.w;
    }
    float wu[8];
#pragma unroll
    for (int i = 0; i < NI; ++i) wu[i] = Winp[n * NI + i];
    wu[6] = 0.0f; wu[7] = 0.0f;

    const float* rptr = rn_in + b * BSTRIDE + n;             // rn' lane view
    const float* uptr = rn_in + b * BSTRIDE + 64 + (n & 7);  // uterm lane view
    float*       xdst = x_out + b * BSTRIDE + n;             // x writeback view

    // ---- init parity 0: x[0] = 0, uterm(0) ----
    xs[0][n] = 0.0f;
    if (n < 8) xs[0][64 + n] = uptr[0];

    // prefetch rings (depth 4, static slots): rnb holds rn'(t), utb holds uterm(t+1)
    float rnb[4], utb[4];
#pragma unroll
    for (int d = 0; d < 4; ++d) {
        rnb[d] = rptr[d * RREC];
        utb[d] = uptr[(d + 1) * RREC];
    }

    float xreg = 0.0f;

#define STEP(tcur, slot, P)                                                   \
    do {                                                                      \
        const float rcur = rnb[slot];                                         \
        const float ucur = utb[slot];   /* uterm(t+1) */                      \
        { const int tp = ((tcur) + 4 < TT - 2) ? (tcur) + 4 : TT - 2;         \
          rnb[slot] = rptr[tp * RREC]; }                                      \
        { const int tq = ((tcur) + 5 < TT - 2) ? (tcur) + 5 : TT - 2;         \
          utb[slot] = uptr[tq * RREC]; }                                      \
        /* read ONLY this lane's half of x: 8 b128 (2 uniform addrs/instr,    \
           same banks -> 2-way = free) */                                     \
        const float4* xrow = reinterpret_cast<const float4*>(&xs[P][hb]);     \
        float a0 = 0.f, a1 = 0.f;      /* P1: own row, own half  */           \
        float c0 = 0.f, c1 = 0.f;      /* P2: partner row, own half */        \
        _Pragma("unroll")                                                     \
        for (int q = 0; q < 8; ++q) {                                         \
            const float4 v = xrow[q];                                         \
            a0 = fmaf(v.x, ws[4*q+0], a0); c0 = fmaf(v.x, wp[4*q+0], c0);     \
            a1 = fmaf(v.y, ws[4*q+1], a1); c1 = fmaf(v.y, wp[4*q+1], c1);     \
            a0 = fmaf(v.z, ws[4*q+2], a0); c0 = fmaf(v.z, wp[4*q+2], c0);     \
            a1 = fmaf(v.w, ws[4*q+3], a1); c1 = fmaf(v.w, wp[4*q+3], c1);     \
        }                                                                     \
        /* uterm: 2 uniform b128 + 6 fma (unsplit) */                         \
        const float4 iv0 = *reinterpret_cast<const float4*>(&xs[P][64]);      \
        const float4 iv1 = *reinterpret_cast<const float4*>(&xs[P][68]);      \
        a0 = fmaf(iv0.x, wu[0], a0); a1 = fmaf(iv0.y, wu[1], a1);             \
        a0 = fmaf(iv0.z, wu[2], a0); a1 = fmaf(iv0.w, wu[3], a1);             \
        a0 = fmaf(iv1.x, wu[4], a0); a1 = fmaf(iv1.y, wu[5], a1);             \
        /* exchange partner half-dot across the lane-32 boundary */           \
        const float p2 = c0 + c1;                                             \
        const float pr = __shfl_xor(p2, 32);                                  \
        const float pre = (a0 + a1) + pr;                                     \
        const float xn  = fmaf(0.9f, xreg,                                    \
                               fmaf(0.1f, fmaxf(pre, 0.f), rcur));            \
        xreg = xn;                                                            \
        xs[(P) ^ 1][n] = xn;                  /* x[t+1] for next step */      \
        if (n < 8) xs[(P) ^ 1][64 + n] = ucur;/* uterm[t+1] */                \
        xdst[(tcur) * RREC] = xn;             /* record[t] <- x[t+1] */       \
    } while (0)

#pragma unroll 1
    for (int t = 0; t < 1020; t += 4) {
        STEP(t + 0, 0, 0);
        STEP(t + 1, 1, 1);
        STEP(t + 2, 2, 0);
        STEP(t + 3, 3, 1);
    }
    STEP(1020, 0, 0);
    STEP(1021, 1, 1);
    STEP(1022, 2, 0);
#undef STEP
}

// ---------------- Pass 3: transpose + fused output projection ----------------
// states[n][t][b] = (t==0) ? 0 : rnu[b][t-1][n];  outputs = states @ Wout^T.
__global__ __launch_bounds__(256) void trans_out(
    const float* __restrict__ rnu,
    const float* __restrict__ Wout,     // (2, 64)
    float* __restrict__ states,         // (64, T, B)
    float* __restrict__ outputs)        // (2, T, B)
{
    const int blk = blockIdx.x;
    const int t   = blk >> 4;
    const int b0  = (blk & 15) * 64;
    const int tid = threadIdx.x;

    __shared__ float xt[64][65];   // [b][n]
    __shared__ float wo[2][64];

    if (tid < 128) wo[tid >> 6][tid & 63] = Wout[tid];

    const int col = tid & 63;
    const int r0  = tid >> 6;
    if (t == 0) {
#pragma unroll
        for (int it = 0; it < 16; ++it) xt[4 * it + r0][col] = 0.0f;
    } else {
#pragma unroll
        for (int it = 0; it < 16; ++it) {
            const int r = 4 * it + r0;   // batch within tile
            xt[r][col] = rnu[(b0 + r) * BSTRIDE + (t - 1) * RREC + col];
        }
    }
    __syncthreads();

#pragma unroll
    for (int it = 0; it < 16; ++it) {
        const int n = 4 * it + r0;
        states[n * TB + t * BB + b0 + col] = xt[col][n];
    }

    if (tid < 128) {
        const int o  = tid >> 6;
        const int bb = tid & 63;
        float acc = 0.0f;
#pragma unroll
        for (int k = 0; k < NN; ++k) acc = fmaf(xt[bb][k], wo[o][k], acc);
        outputs[o * TB + t * BB + b0 + bb] = acc;
    }
}

// ---------------- Fallback (no-workspace path, proven correct) ----------------
#define BARRIER() do {                                                        \
    __builtin_amdgcn_sched_barrier(0);                                        \
    asm volatile("s_waitcnt lgkmcnt(0)\n\ts_barrier" ::: "memory");           \
    __builtin_amdgcn_sched_barrier(0);                                        \
} while (0)

__global__ __launch_bounds__(256, 1) void latent_rnn_fb(
    const float* __restrict__ u, const float* __restrict__ rn,
    const float* __restrict__ inn, const float* __restrict__ Winp,
    const float* __restrict__ Wrec, float* __restrict__ states)
{
    const int hw  = blockIdx.x;
    const int lb  = (hw & 7) * 32 + (hw >> 3);
    const int b0  = lb * 4;
    const int tid = threadIdx.x;
    const int l   = tid & 63;
    const int w   = tid >> 6;
    const int n   = tid >> 2;
    const int bs  = tid & 3;

    __shared__ float rnT[2][NN][5];
    __shared__ float xT[2][NN][5];
    __shared__ float iT[2][4][8];

    float wreg[NN];
#pragma unroll
    for (int k = 0; k < NN; k += 4) {
        const float4 w4 = *reinterpret_cast<const float4*>(Wrec + l * NN + k);
        wreg[k] = w4.x; wreg[k+1] = w4.y; wreg[k+2] = w4.z; wreg[k+3] = w4.w;
    }
    float wi[NI];
#pragma unroll
    for (int i = 0; i < NI; ++i) wi[i] = Winp[l * NI + i];

    const float* rsrc = rn + n * TB + b0 + bs;
    float*       sdst = states + n * TB + b0 + bs;
    const bool  ist  = (tid < NI * 4);
    const int   ii   = tid >> 2;
    const int   ib   = tid & 3;
    const float* usrc = u   + ii * TB + b0 + ib;
    const float* isrc = inn + ii * TB + b0 + ib;

    rnT[0][n][bs] = rsrc[0];
    if (ist) iT[0][ib][ii] = fmaf(NSCALE, isrc[0], usrc[0]);
    xT[0][l][w] = 0.0f;

    float rnPF[4], uPF[4], iPF[4];
#pragma unroll
    for (int d = 0; d < 4; ++d) {
        rnPF[d] = rsrc[(d + 1) * BB];
        if (ist) { uPF[d] = usrc[(d + 1) * BB]; iPF[d] = isrc[(d + 1) * BB]; }
    }
    __syncthreads();

    float xreg = 0.0f;

#define FSTEP(tcur, slot, CC)                                                 \
  {                                                                           \
    sdst[(tcur) * BB] = xT[CC][n][bs];                                        \
    const float rcur = rnT[CC][l][w];                                         \
    const float4 iv0 = *reinterpret_cast<const float4*>(&iT[CC][w][0]);       \
    const float2 iv1 = *reinterpret_cast<const float2*>(&iT[CC][w][4]);       \
    float a0 = 0.f, a1 = 0.f, a2 = 0.f, a3 = 0.f;                             \
    _Pragma("unroll")                                                         \
    for (int k = 0; k < NN; k += 4) {                                         \
        a0 = fmaf(rdlane(xreg, k + 0), wreg[k + 0], a0);                      \
        a1 = fmaf(rdlane(xreg, k + 1), wreg[k + 1], a1);                      \
        a2 = fmaf(rdlane(xreg, k + 2), wreg[k + 2], a2);                      \
        a3 = fmaf(rdlane(xreg, k + 3), wreg[k + 3], a3);                      \
    }                                                                         \
    a0 = fmaf(iv0.x, wi[0], a0); a1 = fmaf(iv0.y, wi[1], a1);                 \
    a2 = fmaf(iv0.z, wi[2], a2); a3 = fmaf(iv0.w, wi[3], a3);                 \
    a0 = fmaf(iv1.x, wi[4], a0); a1 = fmaf(iv1.y, wi[5], a1);                 \
    const float pre = (a0 + a1) + (a2 + a3);                                  \
    const float xn  = fmaf(0.9f, xreg,                                        \
                           fmaf(0.1f, fmaxf(pre, 0.f), ARNSCALE * rcur));     \
    xreg = xn;                                                                \
    xT[(CC) ^ 1][l][w] = xn;                                                  \
    rnT[(CC) ^ 1][n][bs] = rnPF[slot];                                        \
    if (ist) iT[(CC) ^ 1][ib][ii] = fmaf(NSCALE, iPF[slot], uPF[slot]);       \
    { int tp = (tcur) + 5; if (tp > TT - 2) tp = TT - 2;                      \
      rnPF[slot] = rsrc[tp * BB];                                             \
      if (ist) { uPF[slot] = usrc[tp * BB]; iPF[slot] = isrc[tp * BB]; } }    \
    BARRIER();                                                                \
  }

#pragma unroll 1
    for (int t = 0; t < 1020; t += 4) {
        FSTEP(t + 0, 0, 0);
        FSTEP(t + 1, 1, 1);
        FSTEP(t + 2, 2, 0);
        FSTEP(t + 3, 3, 1);
    }
    FSTEP(1020, 0, 0);
    FSTEP(1021, 1, 1);
    FSTEP(1022, 2, 0);
#undef FSTEP

    sdst[(TT - 1) * BB] = xT[1][n][bs];
}

__global__ __launch_bounds__(256) void out_proj(
    const float* __restrict__ states,
    const float* __restrict__ Wout,
    float* __restrict__ outputs)
{
    const int g4 = (blockIdx.x * 256 + threadIdx.x) * 4;
    float4 a0 = {0.f, 0.f, 0.f, 0.f};
    float4 a1 = {0.f, 0.f, 0.f, 0.f};
#pragma unroll
    for (int k = 0; k < NN; ++k) {
        const float4 s = *reinterpret_cast<const float4*>(states + k * TB + g4);
        const float w0 = Wout[k];
        const float w1 = Wout[NN + k];
        a0.x = fmaf(s.x, w0, a0.x); a0.y = fmaf(s.y, w0, a0.y);
        a0.z = fmaf(s.z, w0, a0.z); a0.w = fmaf(s.w, w0, a0.w);
        a1.x = fmaf(s.x, w1, a1.x); a1.y = fmaf(s.y, w1, a1.y);
        a1.z = fmaf(s.z, w1, a1.z); a1.w = fmaf(s.w, w1, a1.w);
    }
    *reinterpret_cast<float4*>(outputs + g4)      = a0;
    *reinterpret_cast<float4*>(outputs + TB + g4) = a1;
}

extern "C" void kernel_launch(void* const* d_in, const int* in_sizes, int n_in,
                              void* d_out, int out_size, void* d_ws, size_t ws_size,
                              hipStream_t stream) {
    const float* u    = (const float*)d_in[0];
    const float* rn   = (const float*)d_in[1];
    const float* inn  = (const float*)d_in[2];
    const float* Winp = (const float*)d_in[3];
    const float* Wrec = (const float*)d_in[4];
    const float* Wout = (const float*)d_in[5];

    float* states  = (float*)d_out;                          // 64*1024*1024
    float* outputs = (float*)d_out + (size_t)NN * TT * BB;   // 2*1024*1024

    const size_t need = (size_t)BB * TT * RREC * sizeof(float);  // ~302 MB
    if (ws_size >= need) {
        float* rnu = (float*)d_ws;
        build_rnu<<<TT * 16, 256, 0, stream>>>(u, rn, inn, rnu);
        latent_rnn_split<<<1024, 64, 0, stream>>>(rnu, rnu, Winp, Wrec);
        trans_out<<<TT * 16, 256, 0, stream>>>(rnu, Wout, states, outputs);
    } else {
        latent_rnn_fb<<<256, 256, 0, stream>>>(u, rn, inn, Winp, Wrec, states);
        out_proj<<<1024, 256, 0, stream>>>(states, Wout, outputs);
    }
}